// Round 1
// baseline (753.111 us; speedup 1.0000x reference)
//
#include <hip/hip_runtime.h>

typedef __attribute__((ext_vector_type(8))) __bf16 bf16x8;
typedef __attribute__((ext_vector_type(4))) float f32x4;

#define AS1(p) ((const __attribute__((address_space(1))) void*)(uintptr_t)(p))
#define AS3(p) ((__attribute__((address_space(3))) void*)(uint32_t)(uintptr_t)(p))
#define GLD16(gp, lp) __builtin_amdgcn_global_load_lds(AS1(gp), AS3(lp), 16, 0, 0)

static constexpr int Bb = 4, Ss = 2048, Hh = 2048, Ih = 8192;
static constexpr int Mm = Bb * Ss;   // 8192 rows

__device__ __forceinline__ float gelu_exact(float x) {
    return 0.5f * x * (1.0f + erff(x * 0.70710678118654752440f));
}

// ---------------- transpose + fp32->bf16 convert: dst[C][R] = (bf16) src[R][C]
__global__ __launch_bounds__(256) void transpose_cvt(const float* __restrict__ src,
                                                     __bf16* __restrict__ dst,
                                                     int R, int C) {
    __shared__ float tile[32][33];
    const int tx = threadIdx.x, ty = threadIdx.y;
    const int cB = blockIdx.x * 32, rB = blockIdx.y * 32;
#pragma unroll
    for (int i = 0; i < 4; ++i)
        tile[ty + i * 8][tx] = src[(size_t)(rB + ty + i * 8) * C + cB + tx];
    __syncthreads();
#pragma unroll
    for (int i = 0; i < 4; ++i)
        dst[(size_t)(cB + ty + i * 8) * R + rB + tx] = (__bf16)tile[tx][ty + i * 8];
}

// ---------------- fused bias + residual add + LayerNorm -> ln(bf16), ra(bf16)
__global__ __launch_bounds__(256) void fused_ln(const float* __restrict__ input,
                                                const float* __restrict__ residual,
                                                const float* __restrict__ bias,
                                                const float* __restrict__ gamma,
                                                const float* __restrict__ beta,
                                                __bf16* __restrict__ lnb,
                                                __bf16* __restrict__ rab) {
    const int row = blockIdx.x;
    const int tid = threadIdx.x;
    const size_t base = (size_t)row * Hh;
    const int e = tid * 8;

    float4 x0 = *(const float4*)(input + base + e);
    float4 x1 = *(const float4*)(input + base + e + 4);
    float4 r0 = *(const float4*)(residual + base + e);
    float4 r1 = *(const float4*)(residual + base + e + 4);
    float4 b0 = *(const float4*)(bias + e);
    float4 b1 = *(const float4*)(bias + e + 4);

    float s[8];
    s[0] = x0.x + r0.x + b0.x; s[1] = x0.y + r0.y + b0.y;
    s[2] = x0.z + r0.z + b0.z; s[3] = x0.w + r0.w + b0.w;
    s[4] = x1.x + r1.x + b1.x; s[5] = x1.y + r1.y + b1.y;
    s[6] = x1.z + r1.z + b1.z; s[7] = x1.w + r1.w + b1.w;

    float sum = 0.f, sq = 0.f;
#pragma unroll
    for (int j = 0; j < 8; ++j) { sum += s[j]; sq += s[j] * s[j]; }
#pragma unroll
    for (int o = 32; o > 0; o >>= 1) {
        sum += __shfl_xor(sum, o);
        sq  += __shfl_xor(sq, o);
    }
    __shared__ float red[8];
    const int wv = tid >> 6, ln_ = tid & 63;
    if (ln_ == 0) { red[wv] = sum; red[4 + wv] = sq; }
    __syncthreads();
    sum = red[0] + red[1] + red[2] + red[3];
    sq  = red[4] + red[5] + red[6] + red[7];

    const float mu   = sum * (1.0f / Hh);
    const float var  = sq * (1.0f / Hh) - mu * mu;
    const float rstd = rsqrtf(var + 1e-6f);

    float4 g0 = *(const float4*)(gamma + e);
    float4 g1 = *(const float4*)(gamma + e + 4);
    float4 t0 = *(const float4*)(beta + e);
    float4 t1 = *(const float4*)(beta + e + 4);
    float g[8] = {g0.x, g0.y, g0.z, g0.w, g1.x, g1.y, g1.z, g1.w};
    float t[8] = {t0.x, t0.y, t0.z, t0.w, t1.x, t1.y, t1.z, t1.w};

    bf16x8 lv, rv;
#pragma unroll
    for (int j = 0; j < 8; ++j) {
        rv[j] = (__bf16)s[j];
        lv[j] = (__bf16)((s[j] - mu) * rstd * g[j] + t[j]);
    }
    *(bf16x8*)(lnb + base + e) = lv;
    *(bf16x8*)(rab + base + e) = rv;
}

// ---------------- bf16 GEMM, B transposed ([N][K]), m97 structure
// MODE 0: out = gelu(A@B^T + bias) -> bf16 h
// MODE 1: out = A@B^T + bias + ra  -> fp32 d_out
template <int MODE>
__global__ __launch_bounds__(256, 2) void gemm_bt(const __bf16* __restrict__ A,
                                                  const __bf16* __restrict__ Bt,
                                                  const float* __restrict__ bias,
                                                  const __bf16* __restrict__ rab,
                                                  __bf16* __restrict__ outH,
                                                  float* __restrict__ outF,
                                                  int M, int N, int K) {
    __shared__ __bf16 lsA[128 * 32];
    __shared__ __bf16 lsB[128 * 32];

    const int tid = threadIdx.x;
    const int mBase = blockIdx.y * 128;
    const int nBase = blockIdx.x * 128;

    // staging: 256 threads x 16B = 4KB per call; tile is 8KB -> 2 calls each
    const __bf16* aSrc0 = A + (size_t)(mBase + (tid >> 2)) * K + (tid & 3) * 8;
    const __bf16* aSrc1 = aSrc0 + (size_t)64 * K;
    const __bf16* bSrc0 = Bt + (size_t)(nBase + (tid >> 2)) * K + (tid & 3) * 8;
    const __bf16* bSrc1 = bSrc0 + (size_t)64 * K;
    __bf16* lA = lsA + tid * 8;
    __bf16* lB = lsB + tid * 8;

    const int wave = tid >> 6, lane = tid & 63;
    const int wr = wave >> 1, wc = wave & 1;
    const int aRow = wr * 64 + (lane & 15);
    const int bRow = wc * 64 + (lane & 15);
    const int kg = lane >> 4;

    f32x4 acc[4][4] = {};

    for (int kt = 0; kt < K; kt += 32) {
        __syncthreads();
        GLD16(aSrc0, lA);
        GLD16(aSrc1, lA + 2048);
        GLD16(bSrc0, lB);
        GLD16(bSrc1, lB + 2048);
        aSrc0 += 32; aSrc1 += 32; bSrc0 += 32; bSrc1 += 32;
        __syncthreads();

        bf16x8 af[4], bfv[4];
#pragma unroll
        for (int m = 0; m < 4; ++m)
            af[m] = *(const bf16x8*)&lsA[(aRow + m * 16) * 32 + kg * 8];
#pragma unroll
        for (int n = 0; n < 4; ++n)
            bfv[n] = *(const bf16x8*)&lsB[(bRow + n * 16) * 32 + kg * 8];
#pragma unroll
        for (int m = 0; m < 4; ++m)
#pragma unroll
            for (int n = 0; n < 4; ++n)
                acc[m][n] = __builtin_amdgcn_mfma_f32_16x16x32_bf16(af[m], bfv[n], acc[m][n], 0, 0, 0);
    }

    // epilogue: D row = (lane>>4)*4 + reg, col = lane&15  [m89/m91 layout]
    const int rBase0 = mBase + wr * 64 + ((lane >> 4) << 2);
    const int cBase0 = nBase + wc * 64 + (lane & 15);
#pragma unroll
    for (int m = 0; m < 4; ++m) {
        const int row = rBase0 + m * 16;
#pragma unroll
        for (int n = 0; n < 4; ++n) {
            const int col = cBase0 + n * 16;
            const float bb = bias[col];
#pragma unroll
            for (int j = 0; j < 4; ++j) {
                const size_t idx = (size_t)(row + j) * N + col;
                float v = acc[m][n][j];
                if (MODE == 0) {
                    outH[idx] = (__bf16)gelu_exact(v + bb);
                } else {
                    outF[idx] = v + bb + (float)rab[idx];
                }
            }
        }
    }
}

extern "C" void kernel_launch(void* const* d_in, const int* in_sizes, int n_in,
                              void* d_out, int out_size, void* d_ws, size_t ws_size,
                              hipStream_t stream) {
    const float* input    = (const float*)d_in[0];
    const float* residual = (const float*)d_in[1];
    // d_in[2] residual_norm: unused by the reference path
    const float* bias     = (const float*)d_in[3];
    const float* gamma    = (const float*)d_in[4];
    const float* beta     = (const float*)d_in[5];
    const float* inter_w  = (const float*)d_in[6];  // [H, I]
    const float* inter_b  = (const float*)d_in[7];  // [I]
    const float* output_w = (const float*)d_in[8];  // [I, H]
    const float* output_b = (const float*)d_in[9];  // [H]
    float* out = (float*)d_out;

    // workspace layout (256 MB total)
    __bf16* w1t  = (__bf16*)d_ws;                 // [I][H]  32 MB
    __bf16* w2t  = w1t + (size_t)Ih * Hh;         // [H][I]  32 MB
    __bf16* lnb  = w2t + (size_t)Hh * Ih;         // [M][H]  32 MB
    __bf16* rab  = lnb + (size_t)Mm * Hh;         // [M][H]  32 MB
    __bf16* hbuf = rab + (size_t)Mm * Hh;         // [M][I] 128 MB

    // 1) weights -> bf16, transposed to [N][K]
    transpose_cvt<<<dim3(Ih / 32, Hh / 32), dim3(32, 8), 0, stream>>>(inter_w, w1t, Hh, Ih);
    transpose_cvt<<<dim3(Hh / 32, Ih / 32), dim3(32, 8), 0, stream>>>(output_w, w2t, Ih, Hh);

    // 2) fused bias+residual add + LayerNorm
    fused_ln<<<Mm, 256, 0, stream>>>(input, residual, bias, gamma, beta, lnb, rab);

    // 3) h = gelu(ln @ inter_w + inter_b)   [M=8192, N=I=8192, K=H=2048]
    gemm_bt<0><<<dim3(Ih / 128, Mm / 128), 256, 0, stream>>>(
        lnb, w1t, inter_b, nullptr, hbuf, nullptr, Mm, Ih, Hh);

    // 4) out = h @ output_w + output_b + residual_add   [M=8192, N=H=2048, K=I=8192]
    gemm_bt<1><<<dim3(Hh / 128, Mm / 128), 256, 0, stream>>>(
        hbuf, w2t, output_b, rab, nullptr, out, Mm, Hh, Ih);
}

// Round 2
// 608.790 us; speedup vs baseline: 1.2371x; 1.2371x over previous
//
#include <hip/hip_runtime.h>

typedef __attribute__((ext_vector_type(8))) __bf16 bf16x8;
typedef __attribute__((ext_vector_type(4))) float f32x4;

#define AS1(p) ((const __attribute__((address_space(1))) void*)(uintptr_t)(p))
#define AS3(p) ((__attribute__((address_space(3))) void*)(uint32_t)(uintptr_t)(p))
#define GLD16(gp, lp) __builtin_amdgcn_global_load_lds(AS1(gp), AS3(lp), 16, 0, 0)

static constexpr int Bb = 4, Ss = 2048, Hh = 2048, Ih = 8192;
static constexpr int Mm = Bb * Ss;   // 8192 rows

__device__ __forceinline__ float gelu_exact(float x) {
    return 0.5f * x * (1.0f + erff(x * 0.70710678118654752440f));
}

// ---------------- transpose + fp32->bf16 convert: dst[C][R] = (bf16) src[R][C]
__global__ __launch_bounds__(256) void transpose_cvt(const float* __restrict__ src,
                                                     __bf16* __restrict__ dst,
                                                     int R, int C) {
    __shared__ float tile[32][33];
    const int tx = threadIdx.x, ty = threadIdx.y;
    const int cB = blockIdx.x * 32, rB = blockIdx.y * 32;
#pragma unroll
    for (int i = 0; i < 4; ++i)
        tile[ty + i * 8][tx] = src[(size_t)(rB + ty + i * 8) * C + cB + tx];
    __syncthreads();
#pragma unroll
    for (int i = 0; i < 4; ++i)
        dst[(size_t)(cB + ty + i * 8) * R + rB + tx] = (__bf16)tile[tx][ty + i * 8];
}

// ---------------- fused bias + residual add + LayerNorm -> ln(bf16), ra(bf16)
__global__ __launch_bounds__(256) void fused_ln(const float* __restrict__ input,
                                                const float* __restrict__ residual,
                                                const float* __restrict__ bias,
                                                const float* __restrict__ gamma,
                                                const float* __restrict__ beta,
                                                __bf16* __restrict__ lnb,
                                                __bf16* __restrict__ rab) {
    const int row = blockIdx.x;
    const int tid = threadIdx.x;
    const size_t base = (size_t)row * Hh;
    const int e = tid * 8;

    float4 x0 = *(const float4*)(input + base + e);
    float4 x1 = *(const float4*)(input + base + e + 4);
    float4 r0 = *(const float4*)(residual + base + e);
    float4 r1 = *(const float4*)(residual + base + e + 4);
    float4 b0 = *(const float4*)(bias + e);
    float4 b1 = *(const float4*)(bias + e + 4);

    float s[8];
    s[0] = x0.x + r0.x + b0.x; s[1] = x0.y + r0.y + b0.y;
    s[2] = x0.z + r0.z + b0.z; s[3] = x0.w + r0.w + b0.w;
    s[4] = x1.x + r1.x + b1.x; s[5] = x1.y + r1.y + b1.y;
    s[6] = x1.z + r1.z + b1.z; s[7] = x1.w + r1.w + b1.w;

    float sum = 0.f, sq = 0.f;
#pragma unroll
    for (int j = 0; j < 8; ++j) { sum += s[j]; sq += s[j] * s[j]; }
#pragma unroll
    for (int o = 32; o > 0; o >>= 1) {
        sum += __shfl_xor(sum, o);
        sq  += __shfl_xor(sq, o);
    }
    __shared__ float red[8];
    const int wv = tid >> 6, ln_ = tid & 63;
    if (ln_ == 0) { red[wv] = sum; red[4 + wv] = sq; }
    __syncthreads();
    sum = red[0] + red[1] + red[2] + red[3];
    sq  = red[4] + red[5] + red[6] + red[7];

    const float mu   = sum * (1.0f / Hh);
    const float var  = sq * (1.0f / Hh) - mu * mu;
    const float rstd = rsqrtf(var + 1e-6f);

    float4 g0 = *(const float4*)(gamma + e);
    float4 g1 = *(const float4*)(gamma + e + 4);
    float4 t0 = *(const float4*)(beta + e);
    float4 t1 = *(const float4*)(beta + e + 4);
    float g[8] = {g0.x, g0.y, g0.z, g0.w, g1.x, g1.y, g1.z, g1.w};
    float t[8] = {t0.x, t0.y, t0.z, t0.w, t1.x, t1.y, t1.z, t1.w};

    bf16x8 lv, rv;
#pragma unroll
    for (int j = 0; j < 8; ++j) {
        rv[j] = (__bf16)s[j];
        lv[j] = (__bf16)((s[j] - mu) * rstd * g[j] + t[j]);
    }
    *(bf16x8*)(lnb + base + e) = lv;
    *(bf16x8*)(rab + base + e) = rv;
}

// ================= 256x256 8-phase bf16 GEMM (m201-style template) =========
// A [M][K] bf16, Bt [N][K] bf16. MODE 0: outH = gelu(A@B^T + bias) bf16.
// MODE 1: outF = A@B^T + bias + (float)rab, fp32.

__device__ __forceinline__ void ldA4(const char* p0, const char* p1, const int mhOff,
                                     bf16x8 (&af)[4][2]) {
#pragma unroll
    for (int m = 0; m < 4; ++m) {
        af[m][0] = *(const bf16x8*)(p0 + mhOff + m * 2048);
        af[m][1] = *(const bf16x8*)(p1 + mhOff + m * 2048);
    }
}
__device__ __forceinline__ void ldB2(const char* p0, const char* p1, const int nhOff,
                                     bf16x8 (&bf)[2][2]) {
#pragma unroll
    for (int n = 0; n < 2; ++n) {
        bf[n][0] = *(const bf16x8*)(p0 + nhOff + n * 2048);
        bf[n][1] = *(const bf16x8*)(p1 + nhOff + n * 2048);
    }
}
template <int MH, int NH>
__device__ __forceinline__ void mfmaQ(const bf16x8 (&af)[4][2], const bf16x8 (&bf)[2][2],
                                      f32x4 (&acc)[8][4]) {
#pragma unroll
    for (int m = 0; m < 4; ++m)
#pragma unroll
        for (int n = 0; n < 2; ++n)
#pragma unroll
            for (int ks = 0; ks < 2; ++ks)
                acc[MH * 4 + m][NH * 2 + n] = __builtin_amdgcn_mfma_f32_16x16x32_bf16(
                    af[m][ks], bf[n][ks], acc[MH * 4 + m][NH * 2 + n], 0, 0, 0);
}
__device__ __forceinline__ void stage2(const __bf16* src, __bf16* dst, const size_t row64) {
    GLD16(src, dst);
    GLD16(src + row64, dst + 4096);
}

#define PHASE_MID                                         \
    __builtin_amdgcn_s_barrier();                         \
    asm volatile("s_waitcnt lgkmcnt(0)" ::: "memory");    \
    __builtin_amdgcn_sched_barrier(0);                    \
    __builtin_amdgcn_s_setprio(1)
#define PHASE_END                                         \
    __builtin_amdgcn_s_setprio(0);                        \
    __builtin_amdgcn_s_barrier()

template <int MODE>
__global__ __launch_bounds__(512, 2) void gemm256(const __bf16* __restrict__ A,
                                                  const __bf16* __restrict__ Bt,
                                                  const float* __restrict__ bias,
                                                  const __bf16* __restrict__ rab,
                                                  __bf16* __restrict__ outH,
                                                  float* __restrict__ outF,
                                                  int M, int N, int K) {
    __shared__ __align__(128) __bf16 lds[2 * 4 * 128 * 64];  // 128 KiB

    const int tid = threadIdx.x;
    // T1: XCD-aware block swizzle (nwg % 8 == 0 for both our grids)
    const int nbx = N >> 8;
    const int nwg = gridDim.x;
    const int cpx = nwg >> 3;
    const int bid = blockIdx.x;
    const int swz = (bid & 7) * cpx + (bid >> 3);
    const int by = swz / nbx, bx = swz - by * nbx;
    const int mBase = by << 8, nBase = bx << 8;

    const int wave = tid >> 6, lane = tid & 63;
    const int wr = wave >> 2, wc = wave & 3;   // 2 x 4 wave grid

    const int NT = K >> 6;       // K-tiles of 64
    const int NI = NT >> 1;      // 2 tiles per iteration

    // --- ds_read pointers (T2 swizzled): slot ^= (row&7); row&7 == lane&7 here
    char* ldsc = (char*)lds;
    const int laneCol0 = (((lane >> 4) << 4)) ^ ((lane & 7) << 4);       // ks=0
    const int laneCol1 = laneCol0 ^ 64;                                  // ks=1
    const int aLaneR = (lane & 15) << 7;
    const int bLaneR = (((wc & 1) << 6) + (lane & 15)) << 7;
    const char* pA[2][2] = {
        {ldsc + (0 * 4 + wr) * 16384 + aLaneR + laneCol0,
         ldsc + (0 * 4 + wr) * 16384 + aLaneR + laneCol1},
        {ldsc + (1 * 4 + wr) * 16384 + aLaneR + laneCol0,
         ldsc + (1 * 4 + wr) * 16384 + aLaneR + laneCol1}};
    const char* pB[2][2] = {
        {ldsc + (0 * 4 + 2 + (wc >> 1)) * 16384 + bLaneR + laneCol0,
         ldsc + (0 * 4 + 2 + (wc >> 1)) * 16384 + bLaneR + laneCol1},
        {ldsc + (1 * 4 + 2 + (wc >> 1)) * 16384 + bLaneR + laneCol0,
         ldsc + (1 * 4 + 2 + (wc >> 1)) * 16384 + bLaneR + laneCol1}};

    // --- staging addresses: LDS linear, global source col-slot pre-swizzled
    const int srow = tid >> 3;                         // 0..63
    const int scol = ((tid & 7) ^ (srow & 7)) << 3;    // element col (16B slots permuted)
    const __bf16* aSt = A + (size_t)(mBase + srow) * K + scol;
    const __bf16* bSt = Bt + (size_t)(nBase + srow) * K + scol;
    __bf16* lw = lds + tid * 8;
    const size_t row64 = (size_t)64 * K;
    const size_t row128 = (size_t)128 * K;

#define STA(buf, h, t) stage2(aSt + (h) * row128 + (size_t)(t) * 64, lw + ((buf) * 4 + (h)) * 8192, row64)
#define STB(buf, h, t) stage2(bSt + (h) * row128 + (size_t)(t) * 64, lw + ((buf) * 4 + 2 + (h)) * 8192, row64)

    f32x4 acc[8][4] = {};
    bf16x8 af[4][2], b0[2][2], b1[2][2];

    // Prologue: tile0 -> buf0 (4 half-tiles), B of tile1 -> buf1
    STA(0, 0, 0); STA(0, 1, 0); STB(0, 0, 0); STB(0, 1, 0);
    STB(1, 0, 1); STB(1, 1, 1);
    asm volatile("s_waitcnt vmcnt(4)" ::: "memory");   // tile0 landed; B(1) in flight
    __builtin_amdgcn_s_barrier();

    for (int i = 0; i < NI; ++i) {
        const int t0 = 2 * i, t1 = 2 * i + 1;
        const bool pf0 = (t0 + 2 < NT);
        const bool pf1 = (t1 + 2 < NT);

        // ph1: quadrant (0,0) of tile t0 (buf0); stage A0(t1)->buf1
        ldA4(pA[0][0], pA[0][1], 0, af);
        ldB2(pB[0][0], pB[0][1], 0, b0);
        STA(1, 0, t1);
        PHASE_MID; mfmaQ<0, 0>(af, b0, acc); PHASE_END;

        // ph2: (0,1); stage A1(t1)->buf1
        ldB2(pB[0][0], pB[0][1], 4096, b1);
        STA(1, 1, t1);
        PHASE_MID; mfmaQ<0, 1>(af, b1, acc); PHASE_END;

        // ph3: (1,1); stage B0(t0+2)->buf0
        ldA4(pA[0][0], pA[0][1], 8192, af);
        if (pf0) STB(0, 0, t0 + 2);
        PHASE_MID; mfmaQ<1, 1>(af, b1, acc); PHASE_END;

        // ph4: (1,0); stage B1(t0+2)->buf0; counted vmcnt
        if (pf0) STB(0, 1, t0 + 2);
        PHASE_MID; mfmaQ<1, 0>(af, b0, acc);
        __builtin_amdgcn_s_setprio(0);
        if (pf0) { asm volatile("s_waitcnt vmcnt(4)" ::: "memory"); }
        else     { asm volatile("s_waitcnt vmcnt(0)" ::: "memory"); }
        __builtin_amdgcn_s_barrier();

        // ph5: (0,0) of tile t1 (buf1); stage A0(t0+2)->buf0
        ldA4(pA[1][0], pA[1][1], 0, af);
        ldB2(pB[1][0], pB[1][1], 0, b0);
        if (pf0) STA(0, 0, t0 + 2);
        PHASE_MID; mfmaQ<0, 0>(af, b0, acc); PHASE_END;

        // ph6: (0,1); stage A1(t0+2)->buf0
        ldB2(pB[1][0], pB[1][1], 4096, b1);
        if (pf0) STA(0, 1, t0 + 2);
        PHASE_MID; mfmaQ<0, 1>(af, b1, acc); PHASE_END;

        // ph7: (1,1); stage B0(t1+2)->buf1
        ldA4(pA[1][0], pA[1][1], 8192, af);
        if (pf1) STB(1, 0, t1 + 2);
        PHASE_MID; mfmaQ<1, 1>(af, b1, acc); PHASE_END;

        // ph8: (1,0); stage B1(t1+2)->buf1; counted vmcnt
        if (pf1) STB(1, 1, t1 + 2);
        PHASE_MID; mfmaQ<1, 0>(af, b0, acc);
        __builtin_amdgcn_s_setprio(0);
        if (pf1) { asm volatile("s_waitcnt vmcnt(4)" ::: "memory"); }
        __builtin_amdgcn_s_barrier();
    }

    // --- epilogue: C/D layout row=(lane>>4)*4+j, col=lane&15 per 16x16 frag
    const int r0 = mBase + wr * 128 + ((lane >> 4) << 2);
    const int c0 = nBase + wc * 64 + (lane & 15);
    float bb[4];
#pragma unroll
    for (int nf = 0; nf < 4; ++nf) bb[nf] = bias[c0 + nf * 16];
#pragma unroll
    for (int mf = 0; mf < 8; ++mf) {
        const int row = r0 + mf * 16;
#pragma unroll
        for (int nf = 0; nf < 4; ++nf) {
            const int col = c0 + nf * 16;
#pragma unroll
            for (int j = 0; j < 4; ++j) {
                const size_t idx = (size_t)(row + j) * N + col;
                const float v = acc[mf][nf][j] + bb[nf];
                if (MODE == 0) {
                    outH[idx] = (__bf16)gelu_exact(v);
                } else {
                    outF[idx] = v + (float)rab[idx];
                }
            }
        }
    }
#undef STA
#undef STB
}

extern "C" void kernel_launch(void* const* d_in, const int* in_sizes, int n_in,
                              void* d_out, int out_size, void* d_ws, size_t ws_size,
                              hipStream_t stream) {
    const float* input    = (const float*)d_in[0];
    const float* residual = (const float*)d_in[1];
    // d_in[2] residual_norm: unused by the reference path
    const float* bias     = (const float*)d_in[3];
    const float* gamma    = (const float*)d_in[4];
    const float* beta     = (const float*)d_in[5];
    const float* inter_w  = (const float*)d_in[6];  // [H, I]
    const float* inter_b  = (const float*)d_in[7];  // [I]
    const float* output_w = (const float*)d_in[8];  // [I, H]
    const float* output_b = (const float*)d_in[9];  // [H]
    float* out = (float*)d_out;

    // workspace layout (256 MB total)
    __bf16* w1t  = (__bf16*)d_ws;                 // [I][H]  32 MB
    __bf16* w2t  = w1t + (size_t)Ih * Hh;         // [H][I]  32 MB
    __bf16* lnb  = w2t + (size_t)Hh * Ih;         // [M][H]  32 MB
    __bf16* rab  = lnb + (size_t)Mm * Hh;         // [M][H]  32 MB
    __bf16* hbuf = rab + (size_t)Mm * Hh;         // [M][I] 128 MB

    // 1) weights -> bf16, transposed to [N][K]
    transpose_cvt<<<dim3(Ih / 32, Hh / 32), dim3(32, 8), 0, stream>>>(inter_w, w1t, Hh, Ih);
    transpose_cvt<<<dim3(Hh / 32, Ih / 32), dim3(32, 8), 0, stream>>>(output_w, w2t, Ih, Hh);

    // 2) fused bias+residual add + LayerNorm
    fused_ln<<<Mm, 256, 0, stream>>>(input, residual, bias, gamma, beta, lnb, rab);

    // 3) h = gelu(ln @ inter_w + inter_b)   [M=8192, N=I=8192, K=H=2048]
    gemm256<0><<<dim3((Mm / 256) * (Ih / 256)), 512, 0, stream>>>(
        lnb, w1t, inter_b, nullptr, hbuf, nullptr, Mm, Ih, Hh);

    // 4) out = h @ output_w + output_b + residual_add   [M=8192, N=H=2048, K=I=8192]
    gemm256<1><<<dim3((Mm / 256) * (Hh / 256)), 512, 0, stream>>>(
        hbuf, w2t, output_b, rab, nullptr, out, Mm, Hh, Ih);
}